// Round 3
// baseline (840.134 us; speedup 1.0000x reference)
//
#include <hip/hip_runtime.h>

// Problem constants (fixed shapes from setup_inputs)
#define BATCH   8
#define DIM     8
#define NPIX    (1024 * 1024)
#define NCLS    5
#define SIGMA_V 0.5f
#define SIGMA_D 3.0f

#define PBLK 128   // blocks per sample
#define TPB  256   // threads per block
#define NWAVE (TPB / 64)
#define STRIDE (PBLK * TPB)          // grid stride in float2-groups
#define ITER  (NPIX / 2 / STRIDE)    // = 16, compile-time trip count

// ws layout: float ws[BATCH][NCLS][10]  -> per (b,c): [count, sumsq, sum[0..7]]
#define ACC50 (NCLS * 10)
#define WS_FLOATS (BATCH * ACC50)

__global__ void lanenet_init_ws(float* __restrict__ ws) {
    int t = blockIdx.x * blockDim.x + threadIdx.x;
    if (t < WS_FLOATS) ws[t] = 0.0f;
}

__device__ __forceinline__ float wave_sum(float v) {
    #pragma unroll
    for (int off = 32; off > 0; off >>= 1)
        v += __shfl_xor(v, off, 64);
    return v;
}

// (256,4): VGPR cap 128. float2-granularity + explicit 2-stage prefetch keeps
// the live set ~100 VGPRs (50 accum + 2x18 stream buffers) so the compiler can
// overlap next-iter loads with current-iter FMAs without spilling.
// R1: VGPR=64 -> full spill, 440us. R2: float4 live set ~130 at the 128 cap,
// ~160us. This version targets ~55us (HBM floor 288MB / 6.3TB/s = 46us).
__global__ __launch_bounds__(TPB, 4) void lanenet_accum(
        const float* __restrict__ emb,
        const int* __restrict__ seg,
        float* __restrict__ ws) {
    const int b = blockIdx.y;
    const float* embB = emb + (size_t)b * DIM * NPIX;
    const int2* segB  = (const int2*)(seg + (size_t)b * NPIX);
    const int t0 = blockIdx.x * TPB + threadIdx.x;   // float2-group index

    float cnt[NCLS];
    float sq[NCLS];
    float sm[NCLS][DIM];
    #pragma unroll
    for (int c = 0; c < NCLS; ++c) {
        cnt[c] = 0.0f; sq[c] = 0.0f;
        #pragma unroll
        for (int d = 0; d < DIM; ++d) sm[c][d] = 0.0f;
    }

    // prefetch iteration 0
    float2 xc[DIM];
    int2 sc = segB[t0];
    #pragma unroll
    for (int d = 0; d < DIM; ++d)
        xc[d] = ((const float2*)(embB + (size_t)d * NPIX))[t0];

    #pragma unroll
    for (int it = 0; it < ITER; ++it) {
        float2 xn[DIM];
        int2 sn;
        if (it + 1 < ITER) {
            const int gn = t0 + (it + 1) * STRIDE;
            sn = segB[gn];
            #pragma unroll
            for (int d = 0; d < DIM; ++d)
                xn[d] = ((const float2*)(embB + (size_t)d * NPIX))[gn];
        }

        #pragma unroll
        for (int p = 0; p < 2; ++p) {
            const int s = p ? sc.y : sc.x;
            float xv[DIM];
            #pragma unroll
            for (int d = 0; d < DIM; ++d)
                xv[d] = p ? xc[d].y : xc[d].x;

            float n2 = 0.0f;
            #pragma unroll
            for (int d = 0; d < DIM; ++d) n2 = fmaf(xv[d], xv[d], n2);

            #pragma unroll
            for (int c = 0; c < NCLS; ++c) {
                const float sel = (s == c) ? 1.0f : 0.0f;
                cnt[c] += sel;
                sq[c]  = fmaf(sel, n2, sq[c]);
                #pragma unroll
                for (int d = 0; d < DIM; ++d)
                    sm[c][d] = fmaf(sel, xv[d], sm[c][d]);
            }
        }

        // rotate buffers (vanishes under full unroll via register renaming)
        if (it + 1 < ITER) {
            sc = sn;
            #pragma unroll
            for (int d = 0; d < DIM; ++d) xc[d] = xn[d];
        }
    }

    // wave-level shuffle reduction -> LDS -> one atomicAdd per accumulator
    // per BLOCK (50 atomics/block).
    __shared__ float red[NWAVE][ACC50];
    const int lane = threadIdx.x & 63;
    const int w = threadIdx.x >> 6;

    #pragma unroll
    for (int c = 0; c < NCLS; ++c) {
        float v = wave_sum(cnt[c]);
        if (lane == 0) red[w][c * 10 + 0] = v;
        v = wave_sum(sq[c]);
        if (lane == 0) red[w][c * 10 + 1] = v;
        #pragma unroll
        for (int d = 0; d < DIM; ++d) {
            v = wave_sum(sm[c][d]);
            if (lane == 0) red[w][c * 10 + 2 + d] = v;
        }
    }
    __syncthreads();

    if (threadIdx.x < ACC50) {
        float s = 0.0f;
        #pragma unroll
        for (int i = 0; i < NWAVE; ++i) s += red[i][threadIdx.x];
        atomicAdd(&ws[(size_t)b * ACC50 + threadIdx.x], s);
    }
}

__global__ void lanenet_finalize(const float* __restrict__ ws,
                                 float* __restrict__ out) {
    __shared__ float lsamp[BATCH];
    const int t = threadIdx.x;
    if (t < BATCH) {
        const float* a = ws + (size_t)t * ACC50;
        float m[NCLS][DIM];
        float var = 0.0f;
        #pragma unroll
        for (int c = 0; c < NCLS; ++c) {
            const float c0 = fmaxf(a[c * 10 + 0], 1.0f);
            const float qq = a[c * 10 + 1];
            float s2 = 0.0f;
            #pragma unroll
            for (int d = 0; d < DIM; ++d) {
                const float s = a[c * 10 + 2 + d];
                m[c][d] = s / c0;
                s2 = fmaf(s, s, s2);
            }
            float ss = qq - s2 / c0;            // sum of squared residuals
            ss = fmaxf(ss, 0.0f);
            var += fmaxf(sqrtf(ss) - SIGMA_V, 0.0f);
        }
        var *= (1.0f / NCLS);

        float dist = 0.0f;
        #pragma unroll
        for (int i = 0; i < NCLS; ++i) {
            #pragma unroll
            for (int j = i + 1; j < NCLS; ++j) {
                float d2 = 0.0f;
                #pragma unroll
                for (int d = 0; d < DIM; ++d) {
                    const float df = m[i][d] - m[j][d];
                    d2 = fmaf(df, df, d2);
                }
                dist += 2.0f * fmaxf(SIGMA_D - sqrtf(d2), 0.0f);
            }
        }
        dist *= (1.0f / (NCLS * (NCLS - 1)));

        lsamp[t] = var + dist;
    }
    __syncthreads();
    if (t == 0) {
        float s = 0.0f;
        #pragma unroll
        for (int b = 0; b < BATCH; ++b) s += lsamp[b];
        out[0] = s * (1.0f / BATCH);
    }
}

extern "C" void kernel_launch(void* const* d_in, const int* in_sizes, int n_in,
                              void* d_out, int out_size, void* d_ws, size_t ws_size,
                              hipStream_t stream) {
    (void)in_sizes; (void)n_in; (void)out_size; (void)ws_size;
    const float* emb = (const float*)d_in[0];
    const int*   seg = (const int*)d_in[1];
    float* out = (float*)d_out;
    float* ws  = (float*)d_ws;

    lanenet_init_ws<<<1, 512, 0, stream>>>(ws);
    dim3 grid(PBLK, BATCH);
    lanenet_accum<<<grid, TPB, 0, stream>>>(emb, seg, ws);
    lanenet_finalize<<<1, 64, 0, stream>>>(ws, out);
}

// Round 4
// 396.011 us; speedup vs baseline: 2.1215x; 2.1215x over previous
//
#include <hip/hip_runtime.h>

// Problem constants (fixed shapes from setup_inputs)
#define BATCH   8
#define DIM     8
#define NPIX    (1024 * 1024)
#define NCLS    5
#define SIGMA_V 0.5f
#define SIGMA_D 3.0f

#define PBLK 128   // blocks per sample
#define TPB  256   // threads per block
#define NWAVE (TPB / 64)

// ws layout: float ws[BATCH][NCLS][10]  -> per (b,c): [count, sumsq, sum[0..7]]
#define ACC50 (NCLS * 10)
#define WS_FLOATS (BATCH * ACC50)

__global__ void lanenet_init_ws(float* __restrict__ ws) {
    int t = blockIdx.x * blockDim.x + threadIdx.x;
    if (t < WS_FLOATS) ws[t] = 0.0f;
}

__device__ __forceinline__ float wave_sum(float v) {
    #pragma unroll
    for (int off = 32; off > 0; off >>= 1)
        v += __shfl_xor(v, off, 64);
    return v;
}

// amdgpu_waves_per_eu(4,4): pin occupancy at exactly 4 waves/EU -> 128-VGPR
// budget the allocator will actually USE. History:
//   R1 (no bounds):        VGPR=64, full spill, accum 440us
//   R2 (__launch_bounds__(256,4)): still spilled (min-waves is only a cap),
//                          accum ~160us
//   R3 (+manual 16x unroll prefetch): VGPR=64, 1.1GB/dispatch scratch
//                          traffic (FETCH 983MB vs 295MB ideal), accum 561us
// The perf-hint pass marks this kernel memory-bound and chases 8 waves/EU,
// spilling the 50 accumulators. min=max=4 removes that incentive.
__global__ void
__attribute__((amdgpu_flat_work_group_size(TPB, TPB), amdgpu_waves_per_eu(4, 4)))
lanenet_accum(const float* __restrict__ emb,
              const int* __restrict__ seg,
              float* __restrict__ ws) {
    const int b = blockIdx.y;
    const float* embB = emb + (size_t)b * DIM * NPIX;
    const int2* segB  = (const int2*)(seg + (size_t)b * NPIX);

    float cnt[NCLS];
    float sq[NCLS];
    float sm[NCLS][DIM];
    #pragma unroll
    for (int c = 0; c < NCLS; ++c) {
        cnt[c] = 0.0f; sq[c] = 0.0f;
        #pragma unroll
        for (int d = 0; d < DIM; ++d) sm[c][d] = 0.0f;
    }

    const int nG = NPIX / 2;               // float2 groups per sample
    const int stride = PBLK * TPB;

    for (int g = blockIdx.x * TPB + threadIdx.x; g < nG; g += stride) {
        int2 s2 = segB[g];
        float2 x[DIM];
        #pragma unroll
        for (int d = 0; d < DIM; ++d)
            x[d] = ((const float2*)(embB + (size_t)d * NPIX))[g];

        #pragma unroll
        for (int p = 0; p < 2; ++p) {
            const int s = p ? s2.y : s2.x;
            float xv[DIM];
            #pragma unroll
            for (int d = 0; d < DIM; ++d)
                xv[d] = p ? x[d].y : x[d].x;

            float n2 = 0.0f;
            #pragma unroll
            for (int d = 0; d < DIM; ++d) n2 = fmaf(xv[d], xv[d], n2);

            #pragma unroll
            for (int c = 0; c < NCLS; ++c) {
                const float sel = (s == c) ? 1.0f : 0.0f;
                cnt[c] += sel;
                sq[c]  = fmaf(sel, n2, sq[c]);
                #pragma unroll
                for (int d = 0; d < DIM; ++d)
                    sm[c][d] = fmaf(sel, xv[d], sm[c][d]);
            }
        }
    }

    // wave-level shuffle reduction -> LDS -> one atomicAdd per accumulator
    // per BLOCK (50 atomics/block).
    __shared__ float red[NWAVE][ACC50];
    const int lane = threadIdx.x & 63;
    const int w = threadIdx.x >> 6;

    #pragma unroll
    for (int c = 0; c < NCLS; ++c) {
        float v = wave_sum(cnt[c]);
        if (lane == 0) red[w][c * 10 + 0] = v;
        v = wave_sum(sq[c]);
        if (lane == 0) red[w][c * 10 + 1] = v;
        #pragma unroll
        for (int d = 0; d < DIM; ++d) {
            v = wave_sum(sm[c][d]);
            if (lane == 0) red[w][c * 10 + 2 + d] = v;
        }
    }
    __syncthreads();

    if (threadIdx.x < ACC50) {
        float s = 0.0f;
        #pragma unroll
        for (int i = 0; i < NWAVE; ++i) s += red[i][threadIdx.x];
        atomicAdd(&ws[(size_t)b * ACC50 + threadIdx.x], s);
    }
}

__global__ void lanenet_finalize(const float* __restrict__ ws,
                                 float* __restrict__ out) {
    __shared__ float lsamp[BATCH];
    const int t = threadIdx.x;
    if (t < BATCH) {
        const float* a = ws + (size_t)t * ACC50;
        float m[NCLS][DIM];
        float var = 0.0f;
        #pragma unroll
        for (int c = 0; c < NCLS; ++c) {
            const float c0 = fmaxf(a[c * 10 + 0], 1.0f);
            const float qq = a[c * 10 + 1];
            float s2 = 0.0f;
            #pragma unroll
            for (int d = 0; d < DIM; ++d) {
                const float s = a[c * 10 + 2 + d];
                m[c][d] = s / c0;
                s2 = fmaf(s, s, s2);
            }
            float ss = qq - s2 / c0;            // sum of squared residuals
            ss = fmaxf(ss, 0.0f);
            var += fmaxf(sqrtf(ss) - SIGMA_V, 0.0f);
        }
        var *= (1.0f / NCLS);

        float dist = 0.0f;
        #pragma unroll
        for (int i = 0; i < NCLS; ++i) {
            #pragma unroll
            for (int j = i + 1; j < NCLS; ++j) {
                float d2 = 0.0f;
                #pragma unroll
                for (int d = 0; d < DIM; ++d) {
                    const float df = m[i][d] - m[j][d];
                    d2 = fmaf(df, df, d2);
                }
                dist += 2.0f * fmaxf(SIGMA_D - sqrtf(d2), 0.0f);
            }
        }
        dist *= (1.0f / (NCLS * (NCLS - 1)));

        lsamp[t] = var + dist;
    }
    __syncthreads();
    if (t == 0) {
        float s = 0.0f;
        #pragma unroll
        for (int b = 0; b < BATCH; ++b) s += lsamp[b];
        out[0] = s * (1.0f / BATCH);
    }
}

extern "C" void kernel_launch(void* const* d_in, const int* in_sizes, int n_in,
                              void* d_out, int out_size, void* d_ws, size_t ws_size,
                              hipStream_t stream) {
    (void)in_sizes; (void)n_in; (void)out_size; (void)ws_size;
    const float* emb = (const float*)d_in[0];
    const int*   seg = (const int*)d_in[1];
    float* out = (float*)d_out;
    float* ws  = (float*)d_ws;

    lanenet_init_ws<<<1, 512, 0, stream>>>(ws);
    dim3 grid(PBLK, BATCH);
    lanenet_accum<<<grid, TPB, 0, stream>>>(emb, seg, ws);
    lanenet_finalize<<<1, 64, 0, stream>>>(ws, out);
}

// Round 5
// 388.386 us; speedup vs baseline: 2.1631x; 1.0196x over previous
//
#include <hip/hip_runtime.h>

// Problem constants (fixed shapes from setup_inputs)
#define BATCH   8
#define DIM     8
#define NPIX    (1024 * 1024)
#define NCLS    5
#define SIGMA_V 0.5f
#define SIGMA_D 3.0f

#define PBLK 256   // blocks per sample (2048 total = 8 blocks/CU)
#define TPB  256   // threads per block = 4 waves
#define NWAVE (TPB / 64)

// ws layout: float ws[BATCH][NCLS][10]  -> per (b,c): [count, sumsq, sum[0..7]]
#define ACC50 (NCLS * 10)
#define WS_FLOATS (BATCH * ACC50)

__global__ void lanenet_init_ws(float* __restrict__ ws) {
    int t = blockIdx.x * blockDim.x + threadIdx.x;
    if (t < WS_FLOATS) ws[t] = 0.0f;
}

__device__ __forceinline__ float wave_sum(float v) {
    #pragma unroll
    for (int off = 32; off > 0; off >>= 1)
        v += __shfl_xor(v, off, 64);
    return v;
}

// Dim-split accumulation: wave w handles dims {2w, 2w+1} over the SAME pixel
// range. Per-thread accumulators: cnt[5] + sq_partial[5] + sm[5][2] = 20
// (vs 50 when one thread handled all 8 dims). Live set ~46 VGPRs -> fits the
// allocator's preferred 64-VGPR/8-waves-per-EU target with ZERO spill.
// History of fighting the allocator instead:
//   R1 (50 acc, no bounds):            VGPR=64, spill, accum 440us
//   R2 (+launch_bounds(256,4)):        still spilled, accum ~160us
//   R3 (+manual prefetch unroll):      VGPR=64, 1.1GB scratch traffic, 561us
//   R4 (+waves_per_eu(4,4)):           accum still ~145us
// sq is decomposed into per-dim-pair partials (summed at reduction, exact).
// seg is read by all 4 waves (same addresses -> L1 broadcast).
__global__ void lanenet_accum(const float* __restrict__ emb,
                              const int* __restrict__ seg,
                              float* __restrict__ ws) {
    const int b = blockIdx.y;
    const float* embB = emb + (size_t)b * DIM * NPIX;
    const int4* segB  = (const int4*)(seg + (size_t)b * NPIX);

    const int w    = threadIdx.x >> 6;   // wave id: dims 2w, 2w+1
    const int lane = threadIdx.x & 63;

    const float4* e0 = (const float4*)(embB + (size_t)(2 * w)     * NPIX);
    const float4* e1 = (const float4*)(embB + (size_t)(2 * w + 1) * NPIX);

    float cnt[NCLS], sq[NCLS], sm0[NCLS], sm1[NCLS];
    #pragma unroll
    for (int c = 0; c < NCLS; ++c) {
        cnt[c] = 0.0f; sq[c] = 0.0f; sm0[c] = 0.0f; sm1[c] = 0.0f;
    }

    const int nG = NPIX / 4;             // float4 groups per sample (262144)
    const int stride = PBLK * 64;        // all waves cover the same g range

    for (int g = blockIdx.x * 64 + lane; g < nG; g += stride) {
        const int4 s4 = segB[g];
        const float4 xa = e0[g];
        const float4 xb = e1[g];

        #pragma unroll
        for (int p = 0; p < 4; ++p) {
            const int s =
                (p == 0) ? s4.x : (p == 1) ? s4.y : (p == 2) ? s4.z : s4.w;
            const float av =
                (p == 0) ? xa.x : (p == 1) ? xa.y : (p == 2) ? xa.z : xa.w;
            const float bv =
                (p == 0) ? xb.x : (p == 1) ? xb.y : (p == 2) ? xb.z : xb.w;

            const float n2 = fmaf(av, av, bv * bv);  // partial |x|^2 (2 dims)

            #pragma unroll
            for (int c = 0; c < NCLS; ++c) {
                const float sel = (s == c) ? 1.0f : 0.0f;
                cnt[c] += sel;                       // all waves; wave0's used
                sq[c]  = fmaf(sel, n2, sq[c]);
                sm0[c] = fmaf(sel, av, sm0[c]);
                sm1[c] = fmaf(sel, bv, sm1[c]);
            }
        }
    }

    // wave shuffle-reduce -> LDS -> 50 atomics per block
    __shared__ float r_cnt[NCLS];
    __shared__ float r_sq[NWAVE][NCLS];
    __shared__ float r_sm[NCLS][DIM];

    #pragma unroll
    for (int c = 0; c < NCLS; ++c) {
        float v = wave_sum(sq[c]);
        if (lane == 0) r_sq[w][c] = v;
        v = wave_sum(sm0[c]);
        if (lane == 0) r_sm[c][2 * w] = v;
        v = wave_sum(sm1[c]);
        if (lane == 0) r_sm[c][2 * w + 1] = v;
        v = wave_sum(cnt[c]);
        if (lane == 0 && w == 0) r_cnt[c] = v;
    }
    __syncthreads();

    if (threadIdx.x < ACC50) {
        const int c = threadIdx.x / 10;
        const int k = threadIdx.x % 10;
        float v;
        if (k == 0)      v = r_cnt[c];
        else if (k == 1) v = r_sq[0][c] + r_sq[1][c] + r_sq[2][c] + r_sq[3][c];
        else             v = r_sm[c][k - 2];
        atomicAdd(&ws[(size_t)b * ACC50 + threadIdx.x], v);
    }
}

__global__ void lanenet_finalize(const float* __restrict__ ws,
                                 float* __restrict__ out) {
    __shared__ float lsamp[BATCH];
    const int t = threadIdx.x;
    if (t < BATCH) {
        const float* a = ws + (size_t)t * ACC50;
        float m[NCLS][DIM];
        float var = 0.0f;
        #pragma unroll
        for (int c = 0; c < NCLS; ++c) {
            const float c0 = fmaxf(a[c * 10 + 0], 1.0f);
            const float qq = a[c * 10 + 1];
            float s2 = 0.0f;
            #pragma unroll
            for (int d = 0; d < DIM; ++d) {
                const float s = a[c * 10 + 2 + d];
                m[c][d] = s / c0;
                s2 = fmaf(s, s, s2);
            }
            float ss = qq - s2 / c0;            // sum of squared residuals
            ss = fmaxf(ss, 0.0f);
            var += fmaxf(sqrtf(ss) - SIGMA_V, 0.0f);
        }
        var *= (1.0f / NCLS);

        float dist = 0.0f;
        #pragma unroll
        for (int i = 0; i < NCLS; ++i) {
            #pragma unroll
            for (int j = i + 1; j < NCLS; ++j) {
                float d2 = 0.0f;
                #pragma unroll
                for (int d = 0; d < DIM; ++d) {
                    const float df = m[i][d] - m[j][d];
                    d2 = fmaf(df, df, d2);
                }
                dist += 2.0f * fmaxf(SIGMA_D - sqrtf(d2), 0.0f);
            }
        }
        dist *= (1.0f / (NCLS * (NCLS - 1)));

        lsamp[t] = var + dist;
    }
    __syncthreads();
    if (t == 0) {
        float s = 0.0f;
        #pragma unroll
        for (int b = 0; b < BATCH; ++b) s += lsamp[b];
        out[0] = s * (1.0f / BATCH);
    }
}

extern "C" void kernel_launch(void* const* d_in, const int* in_sizes, int n_in,
                              void* d_out, int out_size, void* d_ws, size_t ws_size,
                              hipStream_t stream) {
    (void)in_sizes; (void)n_in; (void)out_size; (void)ws_size;
    const float* emb = (const float*)d_in[0];
    const int*   seg = (const int*)d_in[1];
    float* out = (float*)d_out;
    float* ws  = (float*)d_ws;

    lanenet_init_ws<<<1, 512, 0, stream>>>(ws);
    dim3 grid(PBLK, BATCH);
    lanenet_accum<<<grid, TPB, 0, stream>>>(emb, seg, ws);
    lanenet_finalize<<<1, 64, 0, stream>>>(ws, out);
}